// Round 14
// baseline (225.914 us; speedup 1.0000x reference)
//
#include <hip/hip_runtime.h>
#include <hip/hip_bf16.h>
#include <math.h>

#define BB   128
#define NPTS 256
#define NP1  257
#define DD   512
#define HH   512
#define G4   2048
#define TP1  9
#define NEGF -1e18f
#define MTOT (BB * NP1)   // 32896
#define CSC  2.8853900817779268f   // 2*log2(e): tanh(x) = 1 - 2/(exp2(CSC*x)+1)
#define L2E  1.4426950408889634f
#define NFEAT 2056        // 8 n-tiles x 257 m-tiles
#define NGX   144         // 9 m-tiles x 16 n-tiles (gatesx)

typedef __attribute__((ext_vector_type(8))) short bf16x8;
typedef __attribute__((ext_vector_type(8))) unsigned short u16x8;
typedef __attribute__((ext_vector_type(4))) float f32x4;

__device__ __forceinline__ float bf2f(unsigned short u)
{
    union { unsigned int i; float f; } x;
    x.i = (unsigned int)u << 16;
    return x.f;
}

__device__ __forceinline__ float sigm(float x)
{
    return __builtin_amdgcn_rcpf(1.0f + __builtin_amdgcn_exp2f(-x * L2E));
}

__device__ __forceinline__ float fast_tanh(float x)
{
    float e = __builtin_amdgcn_exp2f(x * CSC);
    return 1.0f - 2.0f * __builtin_amdgcn_rcpf(e + 1.0f);
}

__device__ __forceinline__ void gl_lds16(const __hip_bfloat16* g, __hip_bfloat16* l)
{
    __builtin_amdgcn_global_load_lds(
        (const __attribute__((address_space(1))) void*)g,
        (__attribute__((address_space(3))) void*)l, 16, 0, 0);
}

// ---- shared GEMM helpers: swizzled-LDS 128x64 tile, 16x16x32 MFMA ----
__device__ __forceinline__ void stage8(const __hip_bfloat16* const* aptr,
                                       const __hip_bfloat16* const* bptr,
                                       const int* ldsoff,
                                       __hip_bfloat16* A_, __hip_bfloat16* B_, int kt)
{
#pragma unroll
    for (int s = 0; s < 4; ++s) gl_lds16(aptr[s] + kt, A_ + ldsoff[s]);
#pragma unroll
    for (int s = 0; s < 4; ++s) gl_lds16(bptr[s] + kt, B_ + ldsoff[s]);
}

__device__ __forceinline__ void gemm_step(const __hip_bfloat16* A_,
                                          const __hip_bfloat16* B_,
                                          f32x4 (&acc)[4][4],
                                          int wr, int wc, int rA, int kgrp)
{
#pragma unroll
    for (int ks = 0; ks < 2; ++ks) {
        bf16x8 af[4], bfr[4];
#pragma unroll
        for (int fi = 0; fi < 4; ++fi) {
            const int r = wr + fi * 16 + rA;
            const int ch = (ks * 4 + kgrp) ^ (r & 7);
            af[fi] = *(const bf16x8*)(A_ + r * 64 + ch * 8);
        }
#pragma unroll
        for (int fj = 0; fj < 4; ++fj) {
            const int r = wc + fj * 16 + rA;
            const int ch = (ks * 4 + kgrp) ^ (r & 7);
            bfr[fj] = *(const bf16x8*)(B_ + r * 64 + ch * 8);
        }
#pragma unroll
        for (int fi = 0; fi < 4; ++fi)
#pragma unroll
            for (int fj = 0; fj < 4; ++fj)
                acc[fi][fj] = __builtin_amdgcn_mfma_f32_16x16x32_bf16(
                    af[fi], bfr[fj], acc[fi][fj], 0, 0, 0);
    }
}

// counted-vmcnt 2-buffer K-pipeline: never drains vmcnt to 0 in steady state.
#define PIPE_ITER(I, NW, Acur, Bcur, Anxt, Bnxt)                              \
    if ((I) < 7) stage8(aptr, bptr, ldsoff, Anxt, Bnxt, ((I) + 1) * 64);      \
    asm volatile("s_waitcnt vmcnt(" NW ")" ::: "memory");                     \
    __builtin_amdgcn_s_barrier();                                             \
    asm volatile("" ::: "memory");                                            \
    __builtin_amdgcn_s_setprio(1);                                            \
    gemm_step(Acur, Bcur, acc, wr, wc, rA, kgrp);                             \
    __builtin_amdgcn_s_setprio(0);                                            \
    __builtin_amdgcn_s_barrier();                                             \
    asm volatile("" ::: "memory");

#define PIPE_RUN()                                                            \
    stage8(aptr, bptr, ldsoff, As0, Bs0, 0);                                  \
    PIPE_ITER(0, "8", As0, Bs0, As1, Bs1)                                     \
    PIPE_ITER(1, "8", As1, Bs1, As0, Bs0)                                     \
    PIPE_ITER(2, "8", As0, Bs0, As1, Bs1)                                     \
    PIPE_ITER(3, "8", As1, Bs1, As0, Bs0)                                     \
    PIPE_ITER(4, "8", As0, Bs0, As1, Bs1)                                     \
    PIPE_ITER(5, "8", As1, Bs1, As0, Bs0)                                     \
    PIPE_ITER(6, "8", As0, Bs0, As1, Bs1)                                     \
    PIPE_ITER(7, "0", As1, Bs1, As0, Bs0)

// ------------------------------------------- prep (all conversions, one kernel)
// blocks: [0,256) weight transposes | [256] bsum | [257,273) stopm2 (parallel)
//   [273,1425) Xbf | [1425,1681) init h,c | [1681,3729) wih | [3729,5777) whh
//   [5777,22225) attn_mem -> Abf
__global__ __launch_bounds__(256)
void k_prep(const float* __restrict__ hop_wm, const float* __restrict__ attn_wm,
            const float* __restrict__ hop_wq, const float* __restrict__ attn_wq,
            const float* __restrict__ w_ih, const float* __restrict__ w_hh,
            const float* __restrict__ b_ih, const float* __restrict__ b_hh,
            const float* __restrict__ stop, const float* __restrict__ lstm_in,
            const float* __restrict__ init_i, const float* __restrict__ init_h,
            const float* __restrict__ init_c, const float* __restrict__ Amem,
            __hip_bfloat16* __restrict__ Wt2, __hip_bfloat16* __restrict__ WqtH,
            __hip_bfloat16* __restrict__ WqtA, __hip_bfloat16* __restrict__ wih_bf,
            __hip_bfloat16* __restrict__ whh_bf, float* __restrict__ bsum,
            float* __restrict__ stopm2, __hip_bfloat16* __restrict__ Xbf,
            __hip_bfloat16* __restrict__ h_a, float* __restrict__ cbuf,
            __hip_bfloat16* __restrict__ Abf)
{
    const int x = blockIdx.x, t = threadIdx.x;
    if (x < 256) {                        // 64x64 LDS-tiled weight transpose
        __shared__ float S[64][69];
        const int mat  = x >> 6;          // 0 hop_wm | 1 attn_wm | 2 hop_wq | 3 attn_wq
        const int tile = x & 63;
        const int tr = tile >> 3, tc = tile & 7;
        const float* W = (mat == 0) ? hop_wm : (mat == 1) ? attn_wm
                       : (mat == 2) ? hop_wq : attn_wq;
        __hip_bfloat16* O = (mat == 0) ? Wt2 : (mat == 1) ? (Wt2 + (size_t)512 * DD)
                          : (mat == 2) ? WqtH : WqtA;
        const float scale = (mat == 3) ? 1.0f : CSC;
#pragma unroll
        for (int k = 0; k < 4; ++k) {
            const int r = (t >> 4) + k * 16;
            const int c4 = (t & 15) * 4;
            const float4 v = *(const float4*)(W + (size_t)(tr * 64 + r) * 512 + tc * 64 + c4);
            S[r][c4] = v.x; S[r][c4 + 1] = v.y; S[r][c4 + 2] = v.z; S[r][c4 + 3] = v.w;
        }
        __syncthreads();
        const int oc = tc * 64 + (t >> 2);
        const int j0 = (t & 3) * 16;
        __hip_bfloat16 tmp[16];
#pragma unroll
        for (int j = 0; j < 16; ++j)
            tmp[j] = __float2bfloat16(scale * S[j0 + j][t >> 2]);
        *(bf16x8*)(O + (size_t)oc * 512 + tr * 64 + j0)     = *(bf16x8*)&tmp[0];
        *(bf16x8*)(O + (size_t)oc * 512 + tr * 64 + j0 + 8) = *(bf16x8*)&tmp[8];
    } else if (x == 256) {                // bias sum
#pragma unroll
        for (int i = 0; i < 8; ++i) {
            const int idx = t + 256 * i;
            bsum[idx] = b_ih[idx] + b_hh[idx];
        }
    } else if (x < 273) {                 // stopm2: 16 blocks x 64 h, 4 thr/h
        const int h = (x - 257) * 64 + (t >> 2);
        const int q = t & 3;
        const float* W = (h < 512) ? hop_wm : attn_wm;
        const int col = h & 511;
        float a = 0.f;
        const int k0 = q * 128;
        for (int k = k0; k < k0 + 128; ++k)
            a += stop[k] * W[(size_t)k * HH + col];
        a += __shfl_xor(a, 1);
        a += __shfl_xor(a, 2);
        if (q == 0) stopm2[h] = CSC * a;
    } else if (x < 1425) {                // Xbf rows
        const int m = x - 273;
        const int bb = m / TP1, tt = m - bb * TP1;
        const float* src = (tt == 0) ? init_i : (lstm_in + (size_t)(bb * 8 + tt - 1) * DD);
        float2 vv = *(const float2*)(src + 2 * t);
        __hip_bfloat16* o = Xbf + (size_t)m * DD + 2 * t;
        o[0] = __float2bfloat16(vv.x);
        o[1] = __float2bfloat16(vv.y);
    } else if (x < 1681) {                // init h, c
        const int idx = (x - 1425) * 256 + t;
        h_a[idx]  = __float2bfloat16(init_h[idx & (HH - 1)]);
        cbuf[idx] = init_c[idx & (HH - 1)];
    } else if (x < 3729) {                // wih bf16
        const size_t r = (size_t)(x - 1681) * DD;
        wih_bf[r + t]       = __float2bfloat16(w_ih[r + t]);
        wih_bf[r + t + 256] = __float2bfloat16(w_ih[r + t + 256]);
    } else if (x < 5777) {                // whh bf16
        const size_t r = (size_t)(x - 3729) * DD;
        whh_bf[r + t]       = __float2bfloat16(w_hh[r + t]);
        whh_bf[r + t + 256] = __float2bfloat16(w_hh[r + t + 256]);
    } else {                              // attn_mem (+zero stop row) -> bf16
        const int m = (x - 5777) * 2 + (t >> 7);   // row in [0, 32896)
        const int b = m / NP1;
        const int n = m - b * NP1;
        const int c4 = (t & 127) * 4;
        float4 v = make_float4(0.f, 0.f, 0.f, 0.f);
        if (n < NPTS)
            v = *(const float4*)(Amem + ((size_t)(b * NPTS + n)) * DD + c4);
        __hip_bfloat16* o = Abf + (size_t)m * DD + c4;
        o[0] = __float2bfloat16(v.x);
        o[1] = __float2bfloat16(v.y);
        o[2] = __float2bfloat16(v.z);
        o[3] = __float2bfloat16(v.w);
    }
}

// ------------------- E2[m][h] = exp2(CSC*feat)  (merged hop|attn, MFMA bf16)
// blocks [0,2056): feat2 (XCD-remapped, gload A via Abf). blocks [2056,2200):
// gatesx GEMM (independent; fills CUs during feat2 tail).
__global__ __launch_bounds__(256)
void k_feat2(const __hip_bfloat16* __restrict__ A,
             const __hip_bfloat16* __restrict__ Bt,
             const float* __restrict__ stopm2,
             const int* __restrict__ msz,
             __hip_bfloat16* __restrict__ E2,
             const __hip_bfloat16* __restrict__ Xbf,
             const __hip_bfloat16* __restrict__ wih,
             const float* __restrict__ bsum,
             float* __restrict__ gatesx)
{
    const int orig = blockIdx.x;
    const bool isg = (orig >= NFEAT);
    int m0, n0;
    const __hip_bfloat16* Ause;
    const __hip_bfloat16* Buse;
    if (!isg) {
        const int wgid = (orig & 7) * 257 + (orig >> 3);
        m0 = (wgid >> 3) * 128;
        n0 = (wgid & 7) * 128;
        Ause = A;  Buse = Bt;
    } else {
        const int idx = orig - NFEAT;     // 0..143
        m0 = (idx >> 4) * 128;            // 9 m-tiles
        n0 = (idx & 15) * 128;            // 16 n-tiles
        Ause = Xbf;  Buse = wih;
    }

    __shared__ __align__(16) __hip_bfloat16 SM[4][128 * 64];
    __hip_bfloat16* As0 = SM[0];
    __hip_bfloat16* Bs0 = SM[1];
    __hip_bfloat16* As1 = SM[2];
    __hip_bfloat16* Bs1 = SM[3];
    const int tid  = threadIdx.x;
    const int lane = tid & 63;
    const int wid  = tid >> 6;
    const int wr = (wid >> 1) * 64;
    const int wc = (wid & 1) * 64;

    const __hip_bfloat16* aptr[4];
    const __hip_bfloat16* bptr[4];
    int ldsoff[4];
#pragma unroll
    for (int s = 0; s < 4; ++s) {
        const int si = wid * 4 + s;
        const int o = si * 1024 + lane * 16;
        const int row = o >> 7;
        const int chunk = (o >> 4) & 7;
        const int sch = chunk ^ (row & 7);
        aptr[s] = Ause + (size_t)(m0 + row) * DD + sch * 8;
        bptr[s] = Buse + (size_t)(n0 + row) * DD + sch * 8;
        ldsoff[s] = si * 512;
    }

    f32x4 acc[4][4];
#pragma unroll
    for (int i = 0; i < 4; ++i)
#pragma unroll
        for (int j = 0; j < 4; ++j) acc[i][j] = (f32x4){0.f, 0.f, 0.f, 0.f};

    const int rA = lane & 15;
    const int kgrp = lane >> 4;

    PIPE_RUN()

    if (!isg) {
        // epilogue: exp2 + store; skip hop-half rows with n > msz[b] (never read)
        const bool hopblk = (n0 < 512);
#pragma unroll
        for (int fi = 0; fi < 4; ++fi) {
#pragma unroll
            for (int r = 0; r < 4; ++r) {
                const int m = m0 + wr + fi * 16 + (lane >> 4) * 4 + r;
                const int b = m / NP1;
                const int n = m - b * NP1;
                const int ms = msz[b];
                if (hopblk && n > ms) continue;
                const bool addstop = (n == ms);
#pragma unroll
                for (int fj = 0; fj < 4; ++fj) {
                    const int h = n0 + wc + fj * 16 + (lane & 15);
                    float v = acc[fi][fj][r];
                    if (addstop) v += stopm2[h];
                    E2[(size_t)m * 1024 + h] = __float2bfloat16(__builtin_amdgcn_exp2f(v));
                }
            }
        }
    } else {
#pragma unroll
        for (int fi = 0; fi < 4; ++fi) {
#pragma unroll
            for (int r = 0; r < 4; ++r) {
                const int m = m0 + wr + fi * 16 + (lane >> 4) * 4 + r;
#pragma unroll
                for (int fj = 0; fj < 4; ++fj) {
                    const int h = n0 + wc + fj * 16 + (lane & 15);
                    gatesx[(size_t)m * G4 + h] = acc[fi][fj][r] + bsum[h];
                }
            }
        }
    }
}

// ------------------ small GEMM: C = A @ Bt^T, 64x64 tile, 4 waves
// M=1152, N=512 -> grid (18,8) = 144 blocks
__global__ __launch_bounds__(256)
void k_gemm64(const __hip_bfloat16* __restrict__ A,
              const __hip_bfloat16* __restrict__ Bt,
              float* __restrict__ C, int ldc, int expout)
{
    __shared__ __align__(16) __hip_bfloat16 SM[4][64 * 64];   // 8KB each
    __hip_bfloat16* As0 = SM[0];
    __hip_bfloat16* Bs0 = SM[1];
    __hip_bfloat16* As1 = SM[2];
    __hip_bfloat16* Bs1 = SM[3];
    const int tid  = threadIdx.x;
    const int lane = tid & 63;
    const int wid  = tid >> 6;
    const int m0 = blockIdx.x * 64;
    const int n0 = blockIdx.y * 64;

    const __hip_bfloat16* aptr[2];
    const __hip_bfloat16* bptr[2];
    int ldsoff[2];
#pragma unroll
    for (int s = 0; s < 2; ++s) {
        const int si = wid * 2 + s;       // 0..7
        const int o = si * 1024 + lane * 16;
        const int row = o >> 7;
        const int chunk = (o >> 4) & 7;
        const int sch = chunk ^ (row & 7);
        aptr[s] = A + (size_t)(m0 + row) * DD + sch * 8;
        bptr[s] = Bt + (size_t)(n0 + row) * DD + sch * 8;
        ldsoff[s] = si * 512;
    }

    f32x4 acc[4];
#pragma unroll
    for (int j = 0; j < 4; ++j) acc[j] = (f32x4){0.f, 0.f, 0.f, 0.f};

    const int rA = lane & 15;
    const int kgrp = lane >> 4;

#define STG64(Abuf, Bbuf, KT)                                                 \
    _Pragma("unroll")                                                         \
    for (int s_ = 0; s_ < 2; ++s_) {                                          \
        gl_lds16(aptr[s_] + (KT), (Abuf) + ldsoff[s_]);                       \
        gl_lds16(bptr[s_] + (KT), (Bbuf) + ldsoff[s_]);                       \
    }
#define G64STEP(A_, B_)                                                       \
    _Pragma("unroll")                                                         \
    for (int ks = 0; ks < 2; ++ks) {                                          \
        const int ra = wid * 16 + rA;                                         \
        const bf16x8 af = *(const bf16x8*)((A_) + ra * 64                     \
                              + (((ks * 4 + kgrp) ^ (ra & 7)) * 8));          \
        _Pragma("unroll")                                                     \
        for (int fj = 0; fj < 4; ++fj) {                                      \
            const int rb = fj * 16 + rA;                                      \
            const bf16x8 bf_ = *(const bf16x8*)((B_) + rb * 64                \
                              + (((ks * 4 + kgrp) ^ (rb & 7)) * 8));          \
            acc[fj] = __builtin_amdgcn_mfma_f32_16x16x32_bf16(                \
                af, bf_, acc[fj], 0, 0, 0);                                   \
        }                                                                     \
    }
#define G64ITER(I, NW, Acur, Bcur, Anxt, Bnxt)                                \
    if ((I) < 7) { STG64(Anxt, Bnxt, ((I) + 1) * 64) }                        \
    asm volatile("s_waitcnt vmcnt(" NW ")" ::: "memory");                     \
    __builtin_amdgcn_s_barrier();                                             \
    asm volatile("" ::: "memory");                                            \
    __builtin_amdgcn_s_setprio(1);                                            \
    G64STEP(Acur, Bcur)                                                       \
    __builtin_amdgcn_s_setprio(0);                                            \
    __builtin_amdgcn_s_barrier();                                             \
    asm volatile("" ::: "memory");

    STG64(As0, Bs0, 0)
    G64ITER(0, "4", As0, Bs0, As1, Bs1)
    G64ITER(1, "4", As1, Bs1, As0, Bs0)
    G64ITER(2, "4", As0, Bs0, As1, Bs1)
    G64ITER(3, "4", As1, Bs1, As0, Bs0)
    G64ITER(4, "4", As0, Bs0, As1, Bs1)
    G64ITER(5, "4", As1, Bs1, As0, Bs0)
    G64ITER(6, "4", As0, Bs0, As1, Bs1)
    G64ITER(7, "0", As1, Bs1, As0, Bs0)

#pragma unroll
    for (int fj = 0; fj < 4; ++fj) {
#pragma unroll
        for (int r = 0; r < 4; ++r) {
            const int m = m0 + wid * 16 + (lane >> 4) * 4 + r;
            const int h = n0 + fj * 16 + (lane & 15);
            float v = acc[fj][r];
            if (expout) v = __builtin_amdgcn_exp2f(v);
            C[(size_t)m * ldc + h] = v;
        }
    }
}

// ------- fused LSTM step, M=32 partition: grid (4,64) = 256 blocks (1/CU)
__global__ __launch_bounds__(256)
void k_lstm2(const __hip_bfloat16* __restrict__ hin,   // [128][512]
             const __hip_bfloat16* __restrict__ whh,   // [2048][512]
             const float* __restrict__ gx,             // [1152][2048]
             float* __restrict__ cbuf,                 // [128][512]
             __hip_bfloat16* __restrict__ hout,        // [128][512]
             __hip_bfloat16* __restrict__ query,       // [1152][512] bf16
             int t)
{
    __shared__ __align__(16) __hip_bfloat16 As[32 * 512];   // 32 KB
    __shared__ __align__(16) __hip_bfloat16 Bs[32 * 512];   // 32 KB
    __shared__ float Gs[32][36];
    const int tid  = threadIdx.x;
    const int lane = tid & 63;
    const int wid  = tid >> 6;
    const int m0  = blockIdx.x * 32;
    const int hc0 = blockIdx.y * 8;
    const int wy = wid >> 1, wx = wid & 1;

#pragma unroll
    for (int i = 0; i < 8; ++i) {
        const int o = (i * 256 + tid) * 16;
        const int c = o >> 12;
        const int oc = o & 4095;
        const int row = oc >> 7;
        const int ch = (oc >> 4) & 7;
        const int sch = ch ^ (row & 7);
        gl_lds16(hin + (size_t)(m0 + row) * HH + c * 64 + sch * 8, As + (o >> 1));
    }
#pragma unroll
    for (int i = 0; i < 8; ++i) {
        const int o = (i * 256 + tid) * 16;
        const int c = o >> 12;
        const int oc = o & 4095;
        const int row = oc >> 7;
        const int ch = (oc >> 4) & 7;
        const int sch = ch ^ (row & 7);
        const int brow = (row >> 3) * 512 + hc0 + (row & 7);
        gl_lds16(whh + (size_t)brow * HH + c * 64 + sch * 8, Bs + (o >> 1));
    }
    __syncthreads();

    f32x4 acc = (f32x4){0.f, 0.f, 0.f, 0.f};
    const int rr = lane & 15;
    const int kg = lane >> 4;

    __builtin_amdgcn_s_setprio(1);
#pragma unroll
    for (int ks = 0; ks < 16; ++ks) {
        const int c = ks >> 1, sub = ks & 1;
        const __hip_bfloat16* Ab = As + c * 2048;
        const __hip_bfloat16* Bb = Bs + c * 2048;
        const int ra = wy * 16 + rr;
        const int rb = wx * 16 + rr;
        const bf16x8 af  = *(const bf16x8*)(Ab + ra * 64 + (((sub * 4 + kg) ^ (ra & 7)) * 8));
        const bf16x8 bfr = *(const bf16x8*)(Bb + rb * 64 + (((sub * 4 + kg) ^ (rb & 7)) * 8));
        acc = __builtin_amdgcn_mfma_f32_16x16x32_bf16(af, bfr, acc, 0, 0, 0);
    }
    __builtin_amdgcn_s_setprio(0);

#pragma unroll
    for (int r = 0; r < 4; ++r)
        Gs[wy * 16 + (lane >> 4) * 4 + r][wx * 16 + (lane & 15)] = acc[r];
    __syncthreads();

    const int j = tid & 7;
    const int m = tid >> 3;
    const float* gxr = gx + ((size_t)(m0 + m) * TP1 + t) * G4 + hc0 + j;
    float iv = sigm(Gs[m][j]      + gxr[0]);
    float fv = sigm(Gs[m][8 + j]  + gxr[512]);
    float gv = fast_tanh(Gs[m][16 + j] + gxr[1024]);
    float ov = sigm(Gs[m][24 + j] + gxr[1536]);
    const int ci = (m0 + m) * HH + hc0 + j;
    float cv = fv * cbuf[ci] + iv * gv;
    float hv = ov * fast_tanh(cv);
    cbuf[ci] = cv;
    hout[ci] = __float2bfloat16(hv);
    query[((size_t)(m0 + m) * TP1 + t) * HH + hc0 + j] = __float2bfloat16(hv);
}

// ---- score[b,q,n] = Vsum - sum_h 2*v_h / (E_f[n,h]*E_q[q,h] + 1)
// paired-rcp; masked blocks exit WITHOUT writing (NEGF entries never read)
__global__ __launch_bounds__(256)
void k_score(const __hip_bfloat16* __restrict__ E2, int efoff,
             const float* __restrict__ Eq,
             const float* __restrict__ v, const int* __restrict__ msz,
             float* __restrict__ score, int masked)
{
    const int wid  = threadIdx.x >> 6;
    const int lane = threadIdx.x & 63;
    const int n = blockIdx.x * 4 + wid;
    const int b = blockIdx.y;
    if (n >= NP1) return;
    if (masked && n > msz[b]) return;     // dead region: softpv never reads it
    float* sp = score + (size_t)b * TP1 * NP1 + n;
    const u16x8 fu = *(const u16x8*)((const unsigned short*)E2
                                     + ((size_t)b * NP1 + n) * 1024 + efoff + lane * 8);
    float ef[8];
#pragma unroll
    for (int i = 0; i < 8; ++i) ef[i] = bf2f(fu[i]);
    const float4* v4 = (const float4*)v;
    const float4 va = v4[lane * 2], vb = v4[lane * 2 + 1];
    const float vs8 = va.x + va.y + va.z + va.w + vb.x + vb.y + vb.z + vb.w;
    float v2[8] = {2.f*va.x, 2.f*va.y, 2.f*va.z, 2.f*va.w,
                   2.f*vb.x, 2.f*vb.y, 2.f*vb.z, 2.f*vb.w};
#pragma unroll
    for (int q = 0; q < TP1; ++q) {
        const float4* q4 = (const float4*)(Eq + ((size_t)b * TP1 + q) * HH);
        const float4 qa = q4[lane * 2], qb = q4[lane * 2 + 1];
        float eq[8] = {qa.x, qa.y, qa.z, qa.w, qb.x, qb.y, qb.z, qb.w};
        float acc = 0.f;
#pragma unroll
        for (int i = 0; i < 8; i += 2) {
            const float x0 = fmaf(ef[i],     eq[i],     1.0f);
            const float x1 = fmaf(ef[i + 1], eq[i + 1], 1.0f);
            const float num = fmaf(v2[i], x1, v2[i + 1] * x0);
            acc = fmaf(num, __builtin_amdgcn_rcpf(x0 * x1), acc);
        }
        float s = vs8 - acc;
#pragma unroll
        for (int off = 32; off; off >>= 1) s += __shfl_down(s, off);
        if (lane == 0) sp[q * NP1] = s;
    }
}

// ------- softmax over n<=msz for all 9 q, then query2 = p @ featS
// grid (128, 4): block owns 128 cols (1/thread), 2-way n-split
__global__ __launch_bounds__(256)
void k_softpv(const float* __restrict__ score, const __hip_bfloat16* __restrict__ E2,
              const int* __restrict__ msz, __hip_bfloat16* __restrict__ outq)
{
    const int b   = blockIdx.x;
    const int ch  = blockIdx.y;           // 0..3
    const int tid = threadIdx.x;
    const int lane = tid & 63, wid = tid >> 6;
    __shared__ float p[TP1][NP1 + 3];
    __shared__ float comb[TP1][128];
    const int nlim = msz[b] + 1;

    const float* sb = score + (size_t)b * TP1 * NP1;
    for (int q = wid; q < TP1; q += 4) {
        const float* srow = sb + q * NP1;
        float mx = NEGF;
        for (int n = lane; n < nlim; n += 64) mx = fmaxf(mx, srow[n]);
#pragma unroll
        for (int off = 32; off; off >>= 1) mx = fmaxf(mx, __shfl_xor(mx, off));
        float sum = 0.f;
        for (int n = lane; n < nlim; n += 64) {
            float e = __builtin_amdgcn_exp2f((srow[n] - mx) * L2E);
            p[q][n] = e;
            sum += e;
        }
#pragma unroll
        for (int off = 32; off; off >>= 1) sum += __shfl_xor(sum, off);
        float inv = 1.f / sum;
        for (int n = lane; n < nlim; n += 64) p[q][n] *= inv;
    }
    __syncthreads();

    const int ng = tid >> 7;              // 0/1
    const int tc = tid & 127;
    const int col = ch * 128 + tc;
    const unsigned short* fb = (const unsigned short*)E2 + (size_t)b * NP1 * 1024 + col;
    float a[TP1] = {};
    for (int n = ng; n < nlim; n += 2) {
        const float f = __builtin_amdgcn_logf(bf2f(fb[(size_t)n * 1024]));
#pragma unroll
        for (int q = 0; q < TP1; ++q) a[q] += p[q][n] * f;
    }
    if (ng == 1) {
#pragma unroll
        for (int q = 0; q < TP1; ++q) comb[q][tc] = a[q];
    }
    __syncthreads();
    if (ng == 0) {
        __hip_bfloat16* oq = outq + (size_t)(b * TP1) * HH + col;
#pragma unroll
        for (int q = 0; q < TP1; ++q)
            oq[(size_t)q * HH] = __float2bfloat16(a[q] + comb[q][tc]);
    }
}

// ===========================================================================
extern "C" void kernel_launch(void* const* d_in, const int* in_sizes, int n_in,
                              void* d_out, int out_size, void* d_ws, size_t ws_size,
                              hipStream_t stream)
{
    const float* attn_mem  = (const float*)d_in[0];
    const float* lstm_in   = (const float*)d_in[1];
    const int*   mem_sizes = (const int*)d_in[2];
    const float* init_h    = (const float*)d_in[3];
    const float* init_c    = (const float*)d_in[4];
    const float* init_i    = (const float*)d_in[5];
    const float* stop      = (const float*)d_in[6];
    const float* w_ih      = (const float*)d_in[7];
    const float* w_hh      = (const float*)d_in[8];
    const float* b_ih      = (const float*)d_in[9];
    const float* b_hh      = (const float*)d_in[10];
    const float* attn_wm   = (const float*)d_in[11];
    const float* attn_wq   = (const float*)d_in[12];
    const float* attn_v    = (const float*)d_in[13];
    const float* hop_wm    = (const float*)d_in[14];
    const float* hop_wq    = (const float*)d_in[15];
    const float* hop_v     = (const float*)d_in[16];
    float* out = (float*)d_out;

    char* w = (char*)d_ws;
    __hip_bfloat16* Abf    = (__hip_bfloat16*)w;  w += (size_t)MTOT * DD * 2;    // 33.7 MB
    __hip_bfloat16* E2     = (__hip_bfloat16*)w;  w += (size_t)MTOT * 1024 * 2;  // 67.4 MB
    __hip_bfloat16* Xbf    = (__hip_bfloat16*)w;  w += (size_t)BB * TP1 * DD * 2;
    __hip_bfloat16* Wt2    = (__hip_bfloat16*)w;  w += (size_t)1024 * DD * 2;
    __hip_bfloat16* WqtH   = (__hip_bfloat16*)w;  w += (size_t)HH * HH * 2;
    __hip_bfloat16* WqtA   = (__hip_bfloat16*)w;  w += (size_t)HH * HH * 2;
    __hip_bfloat16* wih_bf = (__hip_bfloat16*)w;  w += (size_t)G4 * DD * 2;
    __hip_bfloat16* whh_bf = (__hip_bfloat16*)w;  w += (size_t)G4 * HH * 2;
    __hip_bfloat16* h_a    = (__hip_bfloat16*)w;  w += (size_t)BB * HH * 2;
    __hip_bfloat16* h_b    = (__hip_bfloat16*)w;  w += (size_t)BB * HH * 2;
    __hip_bfloat16* query  = (__hip_bfloat16*)w;  w += (size_t)BB * TP1 * HH * 2;
    __hip_bfloat16* query2 = (__hip_bfloat16*)w;  w += (size_t)BB * TP1 * HH * 2;
    float* gatesx  = (float*)w;  w += (size_t)BB * TP1 * G4 * 4;                 // 9.4 MB
    float* eq      = (float*)w;  w += (size_t)BB * TP1 * HH * 4;
    float* score   = (float*)w;  w += (size_t)BB * TP1 * NP1 * 4;
    float* cbuf    = (float*)w;  w += (size_t)BB * HH * 4;
    float* stopm2  = (float*)w;  w += 1024 * 4;
    float* bsum    = (float*)w;  w += G4 * 4;

    // all conversions + scaled weight transposes + stop projections, one kernel
    k_prep<<<dim3(22225), dim3(256), 0, stream>>>(
        hop_wm, attn_wm, hop_wq, attn_wq, w_ih, w_hh, b_ih, b_hh,
        stop, lstm_in, init_i, init_h, init_c, attn_mem,
        Wt2, WqtH, WqtA, wih_bf, whh_bf, bsum, stopm2, Xbf, h_a, cbuf, Abf);

    // merged feat GEMM -> E2 (mask-skipped hop half) + gatesx GEMM
    k_feat2<<<dim3(NFEAT + NGX), dim3(256), 0, stream>>>(
        Abf, Wt2, stopm2, mem_sizes, E2, Xbf, wih_bf, bsum, gatesx);

    // LSTM: 9 fused steps, 256 blocks each (1 block/CU)
    for (int t = 0; t < TP1; ++t) {
        const __hip_bfloat16* hin = (t & 1) ? h_b : h_a;
        __hip_bfloat16*      hout = (t & 1) ? h_a : h_b;
        k_lstm2<<<dim3(4, 64), dim3(256), 0, stream>>>(hin, whh_bf, gatesx, cbuf, hout, query, t);
    }

    // hop attention (masked): E_q (64-tile GEMM), score, softmax+PV -> query2
    k_gemm64<<<dim3(18, 8), dim3(256), 0, stream>>>(query, WqtH, eq, HH, 1);
    k_score<<<dim3(65, 128), dim3(256), 0, stream>>>(E2, 0, eq, hop_v, mem_sizes, score, 1);
    k_softpv<<<dim3(128, 4), dim3(256), 0, stream>>>(score, E2, mem_sizes, query2);

    // final pointer scores (unmasked) -> d_out
    k_gemm64<<<dim3(18, 8), dim3(256), 0, stream>>>(query2, WqtA, eq, HH, 1);
    k_score<<<dim3(65, 128), dim3(256), 0, stream>>>(E2, 512, eq, attn_v, mem_sizes, out, 0);
}

// Round 15
// 223.160 us; speedup vs baseline: 1.0123x; 1.0123x over previous
//
#include <hip/hip_runtime.h>
#include <hip/hip_bf16.h>
#include <math.h>

#define BB   128
#define NPTS 256
#define NP1  257
#define DD   512
#define HH   512
#define G4   2048
#define TP1  9
#define NEGF -1e18f
#define MTOT (BB * NP1)   // 32896
#define CSC  2.8853900817779268f   // 2*log2(e): tanh(x) = 1 - 2/(exp2(CSC*x)+1)
#define L2E  1.4426950408889634f
#define NFEAT 2056        // 8 n-tiles x 257 m-tiles
#define NGX   144         // 9 m-tiles x 16 n-tiles (gatesx)

typedef __attribute__((ext_vector_type(8))) short bf16x8;
typedef __attribute__((ext_vector_type(8))) unsigned short u16x8;
typedef __attribute__((ext_vector_type(4))) float f32x4;

__device__ __forceinline__ float bf2f(unsigned short u)
{
    union { unsigned int i; float f; } x;
    x.i = (unsigned int)u << 16;
    return x.f;
}

__device__ __forceinline__ float sigm(float x)
{
    return __builtin_amdgcn_rcpf(1.0f + __builtin_amdgcn_exp2f(-x * L2E));
}

__device__ __forceinline__ float fast_tanh(float x)
{
    float e = __builtin_amdgcn_exp2f(x * CSC);
    return 1.0f - 2.0f * __builtin_amdgcn_rcpf(e + 1.0f);
}

__device__ __forceinline__ void gl_lds16(const __hip_bfloat16* g, __hip_bfloat16* l)
{
    __builtin_amdgcn_global_load_lds(
        (const __attribute__((address_space(1))) void*)g,
        (__attribute__((address_space(3))) void*)l, 16, 0, 0);
}

// ---- shared GEMM helpers: swizzled-LDS 128x64 tile, 16x16x32 MFMA ----
__device__ __forceinline__ void stage8(const __hip_bfloat16* const* aptr,
                                       const __hip_bfloat16* const* bptr,
                                       const int* ldsoff,
                                       __hip_bfloat16* A_, __hip_bfloat16* B_, int kt)
{
#pragma unroll
    for (int s = 0; s < 4; ++s) gl_lds16(aptr[s] + kt, A_ + ldsoff[s]);
#pragma unroll
    for (int s = 0; s < 4; ++s) gl_lds16(bptr[s] + kt, B_ + ldsoff[s]);
}

__device__ __forceinline__ void gemm_step(const __hip_bfloat16* A_,
                                          const __hip_bfloat16* B_,
                                          f32x4 (&acc)[4][4],
                                          int wr, int wc, int rA, int kgrp)
{
#pragma unroll
    for (int ks = 0; ks < 2; ++ks) {
        bf16x8 af[4], bfr[4];
#pragma unroll
        for (int fi = 0; fi < 4; ++fi) {
            const int r = wr + fi * 16 + rA;
            const int ch = (ks * 4 + kgrp) ^ (r & 7);
            af[fi] = *(const bf16x8*)(A_ + r * 64 + ch * 8);
        }
#pragma unroll
        for (int fj = 0; fj < 4; ++fj) {
            const int r = wc + fj * 16 + rA;
            const int ch = (ks * 4 + kgrp) ^ (r & 7);
            bfr[fj] = *(const bf16x8*)(B_ + r * 64 + ch * 8);
        }
#pragma unroll
        for (int fi = 0; fi < 4; ++fi)
#pragma unroll
            for (int fj = 0; fj < 4; ++fj)
                acc[fi][fj] = __builtin_amdgcn_mfma_f32_16x16x32_bf16(
                    af[fi], bfr[fj], acc[fi][fj], 0, 0, 0);
    }
}

// counted-vmcnt 2-buffer K-pipeline: never drains vmcnt to 0 in steady state.
#define PIPE_ITER(I, NW, Acur, Bcur, Anxt, Bnxt)                              \
    if ((I) < 7) stage8(aptr, bptr, ldsoff, Anxt, Bnxt, ((I) + 1) * 64);      \
    asm volatile("s_waitcnt vmcnt(" NW ")" ::: "memory");                     \
    __builtin_amdgcn_s_barrier();                                             \
    asm volatile("" ::: "memory");                                            \
    gemm_step(Acur, Bcur, acc, wr, wc, rA, kgrp);                             \
    __builtin_amdgcn_s_barrier();                                             \
    asm volatile("" ::: "memory");

#define PIPE_RUN()                                                            \
    stage8(aptr, bptr, ldsoff, As0, Bs0, 0);                                  \
    PIPE_ITER(0, "8", As0, Bs0, As1, Bs1)                                     \
    PIPE_ITER(1, "8", As1, Bs1, As0, Bs0)                                     \
    PIPE_ITER(2, "8", As0, Bs0, As1, Bs1)                                     \
    PIPE_ITER(3, "8", As1, Bs1, As0, Bs0)                                     \
    PIPE_ITER(4, "8", As0, Bs0, As1, Bs1)                                     \
    PIPE_ITER(5, "8", As1, Bs1, As0, Bs0)                                     \
    PIPE_ITER(6, "8", As0, Bs0, As1, Bs1)                                     \
    PIPE_ITER(7, "0", As1, Bs1, As0, Bs0)

// ------------------------------------------- prep (all conversions, one kernel)
// blocks: [0,256) weight transposes | [256] bsum | [257,273) stopm2 (parallel)
//   [273,1425) Xbf | [1425,1681) init h,c | [1681,3729) wih | [3729,5777) whh
//   [5777,22225) attn_mem -> Abf
__global__ __launch_bounds__(256)
void k_prep(const float* __restrict__ hop_wm, const float* __restrict__ attn_wm,
            const float* __restrict__ hop_wq, const float* __restrict__ attn_wq,
            const float* __restrict__ w_ih, const float* __restrict__ w_hh,
            const float* __restrict__ b_ih, const float* __restrict__ b_hh,
            const float* __restrict__ stop, const float* __restrict__ lstm_in,
            const float* __restrict__ init_i, const float* __restrict__ init_h,
            const float* __restrict__ init_c, const float* __restrict__ Amem,
            __hip_bfloat16* __restrict__ Wt2, __hip_bfloat16* __restrict__ WqtH,
            __hip_bfloat16* __restrict__ WqtA, __hip_bfloat16* __restrict__ wih_bf,
            __hip_bfloat16* __restrict__ whh_bf, float* __restrict__ bsum,
            float* __restrict__ stopm2, __hip_bfloat16* __restrict__ Xbf,
            __hip_bfloat16* __restrict__ h_a, float* __restrict__ cbuf,
            __hip_bfloat16* __restrict__ Abf)
{
    const int x = blockIdx.x, t = threadIdx.x;
    if (x < 256) {                        // 64x64 LDS-tiled weight transpose
        __shared__ float S[64][69];
        const int mat  = x >> 6;          // 0 hop_wm | 1 attn_wm | 2 hop_wq | 3 attn_wq
        const int tile = x & 63;
        const int tr = tile >> 3, tc = tile & 7;
        const float* W = (mat == 0) ? hop_wm : (mat == 1) ? attn_wm
                       : (mat == 2) ? hop_wq : attn_wq;
        __hip_bfloat16* O = (mat == 0) ? Wt2 : (mat == 1) ? (Wt2 + (size_t)512 * DD)
                          : (mat == 2) ? WqtH : WqtA;
        const float scale = (mat == 3) ? 1.0f : CSC;
#pragma unroll
        for (int k = 0; k < 4; ++k) {
            const int r = (t >> 4) + k * 16;
            const int c4 = (t & 15) * 4;
            const float4 v = *(const float4*)(W + (size_t)(tr * 64 + r) * 512 + tc * 64 + c4);
            S[r][c4] = v.x; S[r][c4 + 1] = v.y; S[r][c4 + 2] = v.z; S[r][c4 + 3] = v.w;
        }
        __syncthreads();
        const int oc = tc * 64 + (t >> 2);
        const int j0 = (t & 3) * 16;
        __hip_bfloat16 tmp[16];
#pragma unroll
        for (int j = 0; j < 16; ++j)
            tmp[j] = __float2bfloat16(scale * S[j0 + j][t >> 2]);
        *(bf16x8*)(O + (size_t)oc * 512 + tr * 64 + j0)     = *(bf16x8*)&tmp[0];
        *(bf16x8*)(O + (size_t)oc * 512 + tr * 64 + j0 + 8) = *(bf16x8*)&tmp[8];
    } else if (x == 256) {                // bias sum
#pragma unroll
        for (int i = 0; i < 8; ++i) {
            const int idx = t + 256 * i;
            bsum[idx] = b_ih[idx] + b_hh[idx];
        }
    } else if (x < 273) {                 // stopm2: 16 blocks x 64 h, 4 thr/h
        const int h = (x - 257) * 64 + (t >> 2);
        const int q = t & 3;
        const float* W = (h < 512) ? hop_wm : attn_wm;
        const int col = h & 511;
        float a = 0.f;
        const int k0 = q * 128;
        for (int k = k0; k < k0 + 128; ++k)
            a += stop[k] * W[(size_t)k * HH + col];
        a += __shfl_xor(a, 1);
        a += __shfl_xor(a, 2);
        if (q == 0) stopm2[h] = CSC * a;
    } else if (x < 1425) {                // Xbf rows
        const int m = x - 273;
        const int bb = m / TP1, tt = m - bb * TP1;
        const float* src = (tt == 0) ? init_i : (lstm_in + (size_t)(bb * 8 + tt - 1) * DD);
        float2 vv = *(const float2*)(src + 2 * t);
        __hip_bfloat16* o = Xbf + (size_t)m * DD + 2 * t;
        o[0] = __float2bfloat16(vv.x);
        o[1] = __float2bfloat16(vv.y);
    } else if (x < 1681) {                // init h, c
        const int idx = (x - 1425) * 256 + t;
        h_a[idx]  = __float2bfloat16(init_h[idx & (HH - 1)]);
        cbuf[idx] = init_c[idx & (HH - 1)];
    } else if (x < 3729) {                // wih bf16
        const size_t r = (size_t)(x - 1681) * DD;
        wih_bf[r + t]       = __float2bfloat16(w_ih[r + t]);
        wih_bf[r + t + 256] = __float2bfloat16(w_ih[r + t + 256]);
    } else if (x < 5777) {                // whh bf16
        const size_t r = (size_t)(x - 3729) * DD;
        whh_bf[r + t]       = __float2bfloat16(w_hh[r + t]);
        whh_bf[r + t + 256] = __float2bfloat16(w_hh[r + t + 256]);
    } else {                              // attn_mem (+zero stop row) -> bf16
        const int m = (x - 5777) * 2 + (t >> 7);   // row in [0, 32896)
        const int b = m / NP1;
        const int n = m - b * NP1;
        const int c4 = (t & 127) * 4;
        float4 v = make_float4(0.f, 0.f, 0.f, 0.f);
        if (n < NPTS)
            v = *(const float4*)(Amem + ((size_t)(b * NPTS + n)) * DD + c4);
        __hip_bfloat16* o = Abf + (size_t)m * DD + c4;
        o[0] = __float2bfloat16(v.x);
        o[1] = __float2bfloat16(v.y);
        o[2] = __float2bfloat16(v.z);
        o[3] = __float2bfloat16(v.w);
    }
}

// ------------------- E2[m][h] = exp2(CSC*feat)  (merged hop|attn, MFMA bf16)
// blocks [0,2056): feat2 (XCD-remapped, gload A via Abf). blocks [2056,2200):
// gatesx GEMM. Hop-half tiles fully beyond msz are skipped ENTIRELY (never read).
__global__ __launch_bounds__(256)
void k_feat2(const __hip_bfloat16* __restrict__ A,
             const __hip_bfloat16* __restrict__ Bt,
             const float* __restrict__ stopm2,
             const int* __restrict__ msz,
             __hip_bfloat16* __restrict__ E2,
             const __hip_bfloat16* __restrict__ Xbf,
             const __hip_bfloat16* __restrict__ wih,
             const float* __restrict__ bsum,
             float* __restrict__ gatesx)
{
    const int orig = blockIdx.x;
    const bool isg = (orig >= NFEAT);
    int m0, n0;
    const __hip_bfloat16* Ause;
    const __hip_bfloat16* Buse;
    if (!isg) {
        const int wgid = (orig & 7) * 257 + (orig >> 3);
        m0 = (wgid >> 3) * 128;
        n0 = (wgid & 7) * 128;
        Ause = A;  Buse = Bt;
        // dead-tile skip: hop half (n0<512), tile within ONE batch, all n > msz
        if (n0 < 512) {
            const int b0 = m0 / NP1;
            const int nlo = m0 - b0 * NP1;
            const bool single = (m0 + 127) < (b0 + 1) * NP1;
            if (single && nlo > msz[b0]) return;   // rows never read downstream
        }
    } else {
        const int idx = orig - NFEAT;     // 0..143
        m0 = (idx >> 4) * 128;            // 9 m-tiles
        n0 = (idx & 15) * 128;            // 16 n-tiles
        Ause = Xbf;  Buse = wih;
    }

    __shared__ __align__(16) __hip_bfloat16 SM[4][128 * 64];
    __hip_bfloat16* As0 = SM[0];
    __hip_bfloat16* Bs0 = SM[1];
    __hip_bfloat16* As1 = SM[2];
    __hip_bfloat16* Bs1 = SM[3];
    const int tid  = threadIdx.x;
    const int lane = tid & 63;
    const int wid  = tid >> 6;
    const int wr = (wid >> 1) * 64;
    const int wc = (wid & 1) * 64;

    const __hip_bfloat16* aptr[4];
    const __hip_bfloat16* bptr[4];
    int ldsoff[4];
#pragma unroll
    for (int s = 0; s < 4; ++s) {
        const int si = wid * 4 + s;
        const int o = si * 1024 + lane * 16;
        const int row = o >> 7;
        const int chunk = (o >> 4) & 7;
        const int sch = chunk ^ (row & 7);
        aptr[s] = Ause + (size_t)(m0 + row) * DD + sch * 8;
        bptr[s] = Buse + (size_t)(n0 + row) * DD + sch * 8;
        ldsoff[s] = si * 512;
    }

    f32x4 acc[4][4];
#pragma unroll
    for (int i = 0; i < 4; ++i)
#pragma unroll
        for (int j = 0; j < 4; ++j) acc[i][j] = (f32x4){0.f, 0.f, 0.f, 0.f};

    const int rA = lane & 15;
    const int kgrp = lane >> 4;

    PIPE_RUN()

    if (!isg) {
        // epilogue: exp2 + store; skip hop-half rows with n > msz[b] (never read)
        const bool hopblk = (n0 < 512);
#pragma unroll
        for (int fi = 0; fi < 4; ++fi) {
#pragma unroll
            for (int r = 0; r < 4; ++r) {
                const int m = m0 + wr + fi * 16 + (lane >> 4) * 4 + r;
                const int b = m / NP1;
                const int n = m - b * NP1;
                const int ms = msz[b];
                if (hopblk && n > ms) continue;
                const bool addstop = (n == ms);
#pragma unroll
                for (int fj = 0; fj < 4; ++fj) {
                    const int h = n0 + wc + fj * 16 + (lane & 15);
                    float v = acc[fi][fj][r];
                    if (addstop) v += stopm2[h];
                    E2[(size_t)m * 1024 + h] = __float2bfloat16(__builtin_amdgcn_exp2f(v));
                }
            }
        }
    } else {
#pragma unroll
        for (int fi = 0; fi < 4; ++fi) {
#pragma unroll
            for (int r = 0; r < 4; ++r) {
                const int m = m0 + wr + fi * 16 + (lane >> 4) * 4 + r;
#pragma unroll
                for (int fj = 0; fj < 4; ++fj) {
                    const int h = n0 + wc + fj * 16 + (lane & 15);
                    gatesx[(size_t)m * G4 + h] = acc[fi][fj][r] + bsum[h];
                }
            }
        }
    }
}

// ------------------ small GEMM: C = A @ Bt^T, 64x64 tile, 4 waves
// M=1152, N=512 -> grid (18,8) = 144 blocks
__global__ __launch_bounds__(256)
void k_gemm64(const __hip_bfloat16* __restrict__ A,
              const __hip_bfloat16* __restrict__ Bt,
              float* __restrict__ C, int ldc, int expout)
{
    __shared__ __align__(16) __hip_bfloat16 SM[4][64 * 64];   // 8KB each
    __hip_bfloat16* As0 = SM[0];
    __hip_bfloat16* Bs0 = SM[1];
    __hip_bfloat16* As1 = SM[2];
    __hip_bfloat16* Bs1 = SM[3];
    const int tid  = threadIdx.x;
    const int lane = tid & 63;
    const int wid  = tid >> 6;
    const int m0 = blockIdx.x * 64;
    const int n0 = blockIdx.y * 64;

    const __hip_bfloat16* aptr[2];
    const __hip_bfloat16* bptr[2];
    int ldsoff[2];
#pragma unroll
    for (int s = 0; s < 2; ++s) {
        const int si = wid * 2 + s;       // 0..7
        const int o = si * 1024 + lane * 16;
        const int row = o >> 7;
        const int chunk = (o >> 4) & 7;
        const int sch = chunk ^ (row & 7);
        aptr[s] = A + (size_t)(m0 + row) * DD + sch * 8;
        bptr[s] = Bt + (size_t)(n0 + row) * DD + sch * 8;
        ldsoff[s] = si * 512;
    }

    f32x4 acc[4];
#pragma unroll
    for (int j = 0; j < 4; ++j) acc[j] = (f32x4){0.f, 0.f, 0.f, 0.f};

    const int rA = lane & 15;
    const int kgrp = lane >> 4;

#define STG64(Abuf, Bbuf, KT)                                                 \
    _Pragma("unroll")                                                         \
    for (int s_ = 0; s_ < 2; ++s_) {                                          \
        gl_lds16(aptr[s_] + (KT), (Abuf) + ldsoff[s_]);                       \
        gl_lds16(bptr[s_] + (KT), (Bbuf) + ldsoff[s_]);                       \
    }
#define G64STEP(A_, B_)                                                       \
    _Pragma("unroll")                                                         \
    for (int ks = 0; ks < 2; ++ks) {                                          \
        const int ra = wid * 16 + rA;                                         \
        const bf16x8 af = *(const bf16x8*)((A_) + ra * 64                     \
                              + (((ks * 4 + kgrp) ^ (ra & 7)) * 8));          \
        _Pragma("unroll")                                                     \
        for (int fj = 0; fj < 4; ++fj) {                                      \
            const int rb = fj * 16 + rA;                                      \
            const bf16x8 bf_ = *(const bf16x8*)((B_) + rb * 64                \
                              + (((ks * 4 + kgrp) ^ (rb & 7)) * 8));          \
            acc[fj] = __builtin_amdgcn_mfma_f32_16x16x32_bf16(                \
                af, bf_, acc[fj], 0, 0, 0);                                   \
        }                                                                     \
    }
#define G64ITER(I, NW, Acur, Bcur, Anxt, Bnxt)                                \
    if ((I) < 7) { STG64(Anxt, Bnxt, ((I) + 1) * 64) }                        \
    asm volatile("s_waitcnt vmcnt(" NW ")" ::: "memory");                     \
    __builtin_amdgcn_s_barrier();                                             \
    asm volatile("" ::: "memory");                                            \
    G64STEP(Acur, Bcur)                                                       \
    __builtin_amdgcn_s_barrier();                                             \
    asm volatile("" ::: "memory");

    STG64(As0, Bs0, 0)
    G64ITER(0, "4", As0, Bs0, As1, Bs1)
    G64ITER(1, "4", As1, Bs1, As0, Bs0)
    G64ITER(2, "4", As0, Bs0, As1, Bs1)
    G64ITER(3, "4", As1, Bs1, As0, Bs0)
    G64ITER(4, "4", As0, Bs0, As1, Bs1)
    G64ITER(5, "4", As1, Bs1, As0, Bs0)
    G64ITER(6, "4", As0, Bs0, As1, Bs1)
    G64ITER(7, "0", As1, Bs1, As0, Bs0)

#pragma unroll
    for (int fj = 0; fj < 4; ++fj) {
#pragma unroll
        for (int r = 0; r < 4; ++r) {
            const int m = m0 + wid * 16 + (lane >> 4) * 4 + r;
            const int h = n0 + fj * 16 + (lane & 15);
            float v = acc[fj][r];
            if (expout) v = __builtin_amdgcn_exp2f(v);
            C[(size_t)m * ldc + h] = v;
        }
    }
}

// ------- fused LSTM step, M=32 partition: grid (4,64) = 256 blocks (1/CU)
__global__ __launch_bounds__(256)
void k_lstm2(const __hip_bfloat16* __restrict__ hin,   // [128][512]
             const __hip_bfloat16* __restrict__ whh,   // [2048][512]
             const float* __restrict__ gx,             // [1152][2048]
             float* __restrict__ cbuf,                 // [128][512]
             __hip_bfloat16* __restrict__ hout,        // [128][512]
             __hip_bfloat16* __restrict__ query,       // [1152][512] bf16
             int t)
{
    __shared__ __align__(16) __hip_bfloat16 As[32 * 512];   // 32 KB
    __shared__ __align__(16) __hip_bfloat16 Bs[32 * 512];   // 32 KB
    __shared__ float Gs[32][36];
    const int tid  = threadIdx.x;
    const int lane = tid & 63;
    const int wid  = tid >> 6;
    const int m0  = blockIdx.x * 32;
    const int hc0 = blockIdx.y * 8;
    const int wy = wid >> 1, wx = wid & 1;

#pragma unroll
    for (int i = 0; i < 8; ++i) {
        const int o = (i * 256 + tid) * 16;
        const int c = o >> 12;
        const int oc = o & 4095;
        const int row = oc >> 7;
        const int ch = (oc >> 4) & 7;
        const int sch = ch ^ (row & 7);
        gl_lds16(hin + (size_t)(m0 + row) * HH + c * 64 + sch * 8, As + (o >> 1));
    }
#pragma unroll
    for (int i = 0; i < 8; ++i) {
        const int o = (i * 256 + tid) * 16;
        const int c = o >> 12;
        const int oc = o & 4095;
        const int row = oc >> 7;
        const int ch = (oc >> 4) & 7;
        const int sch = ch ^ (row & 7);
        const int brow = (row >> 3) * 512 + hc0 + (row & 7);
        gl_lds16(whh + (size_t)brow * HH + c * 64 + sch * 8, Bs + (o >> 1));
    }
    __syncthreads();

    f32x4 acc = (f32x4){0.f, 0.f, 0.f, 0.f};
    const int rr = lane & 15;
    const int kg = lane >> 4;

#pragma unroll
    for (int ks = 0; ks < 16; ++ks) {
        const int c = ks >> 1, sub = ks & 1;
        const __hip_bfloat16* Ab = As + c * 2048;
        const __hip_bfloat16* Bb = Bs + c * 2048;
        const int ra = wy * 16 + rr;
        const int rb = wx * 16 + rr;
        const bf16x8 af  = *(const bf16x8*)(Ab + ra * 64 + (((sub * 4 + kg) ^ (ra & 7)) * 8));
        const bf16x8 bfr = *(const bf16x8*)(Bb + rb * 64 + (((sub * 4 + kg) ^ (rb & 7)) * 8));
        acc = __builtin_amdgcn_mfma_f32_16x16x32_bf16(af, bfr, acc, 0, 0, 0);
    }

#pragma unroll
    for (int r = 0; r < 4; ++r)
        Gs[wy * 16 + (lane >> 4) * 4 + r][wx * 16 + (lane & 15)] = acc[r];
    __syncthreads();

    const int j = tid & 7;
    const int m = tid >> 3;
    const float* gxr = gx + ((size_t)(m0 + m) * TP1 + t) * G4 + hc0 + j;
    float iv = sigm(Gs[m][j]      + gxr[0]);
    float fv = sigm(Gs[m][8 + j]  + gxr[512]);
    float gv = fast_tanh(Gs[m][16 + j] + gxr[1024]);
    float ov = sigm(Gs[m][24 + j] + gxr[1536]);
    const int ci = (m0 + m) * HH + hc0 + j;
    float cv = fv * cbuf[ci] + iv * gv;
    float hv = ov * fast_tanh(cv);
    cbuf[ci] = cv;
    hout[ci] = __float2bfloat16(hv);
    query[((size_t)(m0 + m) * TP1 + t) * HH + hc0 + j] = __float2bfloat16(hv);
}

// ---- score[b,q,n] = Vsum - sum_h 2*v_h / (E_f[n,h]*E_q[q,h] + 1)
// paired-rcp; masked blocks exit WITHOUT writing (NEGF entries never read)
__global__ __launch_bounds__(256)
void k_score(const __hip_bfloat16* __restrict__ E2, int efoff,
             const float* __restrict__ Eq,
             const float* __restrict__ v, const int* __restrict__ msz,
             float* __restrict__ score, int masked)
{
    const int wid  = threadIdx.x >> 6;
    const int lane = threadIdx.x & 63;
    const int n = blockIdx.x * 4 + wid;
    const int b = blockIdx.y;
    if (n >= NP1) return;
    if (masked && n > msz[b]) return;     // dead region: softpv never reads it
    float* sp = score + (size_t)b * TP1 * NP1 + n;
    const u16x8 fu = *(const u16x8*)((const unsigned short*)E2
                                     + ((size_t)b * NP1 + n) * 1024 + efoff + lane * 8);
    float ef[8];
#pragma unroll
    for (int i = 0; i < 8; ++i) ef[i] = bf2f(fu[i]);
    const float4* v4 = (const float4*)v;
    const float4 va = v4[lane * 2], vb = v4[lane * 2 + 1];
    const float vs8 = va.x + va.y + va.z + va.w + vb.x + vb.y + vb.z + vb.w;
    float v2[8] = {2.f*va.x, 2.f*va.y, 2.f*va.z, 2.f*va.w,
                   2.f*vb.x, 2.f*vb.y, 2.f*vb.z, 2.f*vb.w};
#pragma unroll
    for (int q = 0; q < TP1; ++q) {
        const float4* q4 = (const float4*)(Eq + ((size_t)b * TP1 + q) * HH);
        const float4 qa = q4[lane * 2], qb = q4[lane * 2 + 1];
        float eq[8] = {qa.x, qa.y, qa.z, qa.w, qb.x, qb.y, qb.z, qb.w};
        float acc = 0.f;
#pragma unroll
        for (int i = 0; i < 8; i += 2) {
            const float x0 = fmaf(ef[i],     eq[i],     1.0f);
            const float x1 = fmaf(ef[i + 1], eq[i + 1], 1.0f);
            const float num = fmaf(v2[i], x1, v2[i + 1] * x0);
            acc = fmaf(num, __builtin_amdgcn_rcpf(x0 * x1), acc);
        }
        float s = vs8 - acc;
#pragma unroll
        for (int off = 32; off; off >>= 1) s += __shfl_down(s, off);
        if (lane == 0) sp[q * NP1] = s;
    }
}

// ------- softmax over n<=msz for all 9 q, then query2 = p @ featS
// grid (128, 4): block owns 128 cols (1/thread), 2-way n-split
__global__ __launch_bounds__(256)
void k_softpv(const float* __restrict__ score, const __hip_bfloat16* __restrict__ E2,
              const int* __restrict__ msz, __hip_bfloat16* __restrict__ outq)
{
    const int b   = blockIdx.x;
    const int ch  = blockIdx.y;           // 0..3
    const int tid = threadIdx.x;
    const int lane = tid & 63, wid = tid >> 6;
    __shared__ float p[TP1][NP1 + 3];
    __shared__ float comb[TP1][128];
    const int nlim = msz[b] + 1;

    const float* sb = score + (size_t)b * TP1 * NP1;
    for (int q = wid; q < TP1; q += 4) {
        const float* srow = sb + q * NP1;
        float mx = NEGF;
        for (int n = lane; n < nlim; n += 64) mx = fmaxf(mx, srow[n]);
#pragma unroll
        for (int off = 32; off; off >>= 1) mx = fmaxf(mx, __shfl_xor(mx, off));
        float sum = 0.f;
        for (int n = lane; n < nlim; n += 64) {
            float e = __builtin_amdgcn_exp2f((srow[n] - mx) * L2E);
            p[q][n] = e;
            sum += e;
        }
#pragma unroll
        for (int off = 32; off; off >>= 1) sum += __shfl_xor(sum, off);
        float inv = 1.f / sum;
        for (int n = lane; n < nlim; n += 64) p[q][n] *= inv;
    }
    __syncthreads();

    const int ng = tid >> 7;              // 0/1
    const int tc = tid & 127;
    const int col = ch * 128 + tc;
    const unsigned short* fb = (const unsigned short*)E2 + (size_t)b * NP1 * 1024 + col;
    float a[TP1] = {};
    for (int n = ng; n < nlim; n += 2) {
        const float f = __builtin_amdgcn_logf(bf2f(fb[(size_t)n * 1024]));
#pragma unroll
        for (int q = 0; q < TP1; ++q) a[q] += p[q][n] * f;
    }
    if (ng == 1) {
#pragma unroll
        for (int q = 0; q < TP1; ++q) comb[q][tc] = a[q];
    }
    __syncthreads();
    if (ng == 0) {
        __hip_bfloat16* oq = outq + (size_t)(b * TP1) * HH + col;
#pragma unroll
        for (int q = 0; q < TP1; ++q)
            oq[(size_t)q * HH] = __float2bfloat16(a[q] + comb[q][tc]);
    }
}

// ===========================================================================
extern "C" void kernel_launch(void* const* d_in, const int* in_sizes, int n_in,
                              void* d_out, int out_size, void* d_ws, size_t ws_size,
                              hipStream_t stream)
{
    const float* attn_mem  = (const float*)d_in[0];
    const float* lstm_in   = (const float*)d_in[1];
    const int*   mem_sizes = (const int*)d_in[2];
    const float* init_h    = (const float*)d_in[3];
    const float* init_c    = (const float*)d_in[4];
    const float* init_i    = (const float*)d_in[5];
    const float* stop      = (const float*)d_in[6];
    const float* w_ih      = (const float*)d_in[7];
    const float* w_hh      = (const float*)d_in[8];
    const float* b_ih      = (const float*)d_in[9];
    const float* b_hh      = (const float*)d_in[10];
    const float* attn_wm   = (const float*)d_in[11];
    const float* attn_wq   = (const float*)d_in[12];
    const float* attn_v    = (const float*)d_in[13];
    const float* hop_wm    = (const float*)d_in[14];
    const float* hop_wq    = (const float*)d_in[15];
    const float* hop_v     = (const float*)d_in[16];
    float* out = (float*)d_out;

    char* w = (char*)d_ws;
    __hip_bfloat16* Abf    = (__hip_bfloat16*)w;  w += (size_t)MTOT * DD * 2;    // 33.7 MB
    __hip_bfloat16* E2     = (__hip_bfloat16*)w;  w += (size_t)MTOT * 1024 * 2;  // 67.4 MB
    __hip_bfloat16* Xbf    = (__hip_bfloat16*)w;  w += (size_t)BB * TP1 * DD * 2;
    __hip_bfloat16* Wt2    = (__hip_bfloat16*)w;  w += (size_t)1024 * DD * 2;
    __hip_bfloat16* WqtH   = (__hip_bfloat16*)w;  w += (size_t)HH * HH * 2;
    __hip_bfloat16* WqtA   = (__hip_bfloat16*)w;  w += (size_t)HH * HH * 2;
    __hip_bfloat16* wih_bf = (__hip_bfloat16*)w;  w += (size_t)G4 * DD * 2;
    __hip_bfloat16* whh_bf = (__hip_bfloat16*)w;  w += (size_t)G4 * HH * 2;
    __hip_bfloat16* h_a    = (__hip_bfloat16*)w;  w += (size_t)BB * HH * 2;
    __hip_bfloat16* h_b    = (__hip_bfloat16*)w;  w += (size_t)BB * HH * 2;
    __hip_bfloat16* query  = (__hip_bfloat16*)w;  w += (size_t)BB * TP1 * HH * 2;
    __hip_bfloat16* query2 = (__hip_bfloat16*)w;  w += (size_t)BB * TP1 * HH * 2;
    float* gatesx  = (float*)w;  w += (size_t)BB * TP1 * G4 * 4;                 // 9.4 MB
    float* eq      = (float*)w;  w += (size_t)BB * TP1 * HH * 4;
    float* score   = (float*)w;  w += (size_t)BB * TP1 * NP1 * 4;
    float* cbuf    = (float*)w;  w += (size_t)BB * HH * 4;
    float* stopm2  = (float*)w;  w += 1024 * 4;
    float* bsum    = (float*)w;  w += G4 * 4;

    // all conversions + scaled weight transposes + stop projections, one kernel
    k_prep<<<dim3(22225), dim3(256), 0, stream>>>(
        hop_wm, attn_wm, hop_wq, attn_wq, w_ih, w_hh, b_ih, b_hh,
        stop, lstm_in, init_i, init_h, init_c, attn_mem,
        Wt2, WqtH, WqtA, wih_bf, whh_bf, bsum, stopm2, Xbf, h_a, cbuf, Abf);

    // merged feat GEMM -> E2 (dead-tile + mask-skipped hop half) + gatesx GEMM
    k_feat2<<<dim3(NFEAT + NGX), dim3(256), 0, stream>>>(
        Abf, Wt2, stopm2, mem_sizes, E2, Xbf, wih_bf, bsum, gatesx);

    // LSTM: 9 fused steps, 256 blocks each (1 block/CU)
    for (int t = 0; t < TP1; ++t) {
        const __hip_bfloat16* hin = (t & 1) ? h_b : h_a;
        __hip_bfloat16*      hout = (t & 1) ? h_a : h_b;
        k_lstm2<<<dim3(4, 64), dim3(256), 0, stream>>>(hin, whh_bf, gatesx, cbuf, hout, query, t);
    }

    // hop attention (masked): E_q (64-tile GEMM), score, softmax+PV -> query2
    k_gemm64<<<dim3(18, 8), dim3(256), 0, stream>>>(query, WqtH, eq, HH, 1);
    k_score<<<dim3(65, 128), dim3(256), 0, stream>>>(E2, 0, eq, hop_v, mem_sizes, score, 1);
    k_softpv<<<dim3(128, 4), dim3(256), 0, stream>>>(score, E2, mem_sizes, query2);

    // final pointer scores (unmasked) -> d_out
    k_gemm64<<<dim3(18, 8), dim3(256), 0, stream>>>(query2, WqtA, eq, HH, 1);
    k_score<<<dim3(65, 128), dim3(256), 0, stream>>>(E2, 512, eq, attn_v, mem_sizes, out, 0);
}